// Round 10
// baseline (870.718 us; speedup 1.0000x reference)
//
#include <hip/hip_runtime.h>
#include <hip/hip_cooperative_groups.h>

namespace cg = cooperative_groups;

#define N_NODES 50000
#define N_EDGES 600000
#define D 128
#define NLAYERS 3
#define CSR_CAP (N_EDGES + 3 * N_NODES)
#define NTILES ((N_NODES + 31) / 32)         // 1563
#define NGROUPS (N_NODES / 16)               // 3125 (exact)
#define CPITCH 136

#define CVT_A (N_NODES * D / 4)              // 1,600,000
#define CVT_B (NLAYERS * D * 256)            // 98,304
#define CVT_TOTAL (CVT_A + CVT_B + N_NODES)  // 1,748,304

typedef __attribute__((ext_vector_type(8))) short short8;
typedef __attribute__((ext_vector_type(4))) float floatx4;

__device__ __forceinline__ float bf_lo(unsigned u) { return __uint_as_float(u << 16); }
__device__ __forceinline__ float bf_hi(unsigned u) { return __uint_as_float(u & 0xffff0000u); }
__device__ __forceinline__ unsigned short f2bf(float f) {
    unsigned u = __float_as_uint(f);
    return (unsigned short)((u + 0x7fffu + ((u >> 16) & 1u)) >> 16);
}

struct Params {
    const float* x;
    const int* src;
    const int* dst;
    const float* Wl;
    const float* bl;
    const float* Wr;
    const float* Wout;
    const float* bout;
    float* out;
    unsigned short* xb;
    unsigned short* hb;
    unsigned short* aggb;
    unsigned short* WtF;
    int* deg;
    int* row_start;
    int* cursor;
    float* inv_deg;
    int* csr_src;
    int* counter;
};

// ---------------- shared phase bodies (used by mega + fallback) ----------------

__device__ __forceinline__ void phase_cvt(const Params& p, int bx, int gs) {
    for (int i = bx * 256 + (int)threadIdx.x; i < CVT_TOTAL; i += gs * 256) {
        if (i < CVT_A) {
            float4 v = ((const float4*)p.x)[i];
            ushort4 o;
            o.x = f2bf(v.x); o.y = f2bf(v.y); o.z = f2bf(v.z); o.w = f2bf(v.w);
            ((ushort4*)p.xb)[i] = o;
        } else if (i < CVT_A + CVT_B) {
            int t = i - CVT_A;
            int l = t >> 15;
            int r = t & 32767;
            int f = r >> 3;
            int ii = r & 7;
            int jkt = f >> 6;
            int lane = f & 63;
            int j = jkt >> 3;
            int kt = jkt & 7;
            int half = lane & 15;
            int quad = lane >> 4;
            int n = j * 16 + half;
            int k = kt * 32 + quad * 8 + ii;
            float v = (k < D) ? p.Wl[(size_t)l * D * D + (size_t)k * D + n]
                              : p.Wr[(size_t)l * D * D + (size_t)(k - D) * D + n];
            p.WtF[t] = f2bf(v);
        } else {
            int j = i - (CVT_A + CVT_B);
            p.deg[j] = 0;
            p.cursor[j] = 0;
            if (j == 0) p.counter[0] = 0;
            if (j < D) {
                p.xb[(size_t)N_NODES * D + j] = 0;
                p.hb[(size_t)N_NODES * D + j] = 0;
            }
        }
    }
}

__device__ __forceinline__ void phase_hist(const Params& p, int bx, int gs) {
    for (int e = bx * 256 + (int)threadIdx.x; e < N_EDGES; e += gs * 256)
        atomicAdd(&p.deg[p.dst[e]], 1);
}

__device__ __forceinline__ void phase_alloc(const Params& p, int bx, int gs) {
    int tid = threadIdx.x;
    int lane = tid & 63;
    int gw = bx * 4 + (tid >> 6);
    for (int base = gw * 64; base < N_NODES; base += gs * 4 * 64) {
        int i = base + lane;
        int d = (i < N_NODES) ? p.deg[i] : 0;
        int pd = (d + 3) & ~3;
        int v = pd;
        #pragma unroll
        for (int off = 1; off < 64; off <<= 1) {
            int t = __shfl_up(v, off, 64);
            if (lane >= off) v += t;
        }
        int total = __shfl(v, 63, 64);
        int b = 0;
        if (lane == 63) b = atomicAdd(p.counter, total);
        b = __shfl(b, 63, 64);
        if (i < N_NODES) {
            int rs = b + v - pd;
            p.row_start[i] = rs;
            p.inv_deg[i] = 1.0f / fmaxf((float)d, 1.0f);
            for (int k = d; k < pd; k++) p.csr_src[rs + k] = N_NODES;
        }
    }
}

__device__ __forceinline__ void phase_fill(const Params& p, int bx, int gs) {
    for (int e = bx * 256 + (int)threadIdx.x; e < N_EDGES; e += gs * 256) {
        int d_ = p.dst[e];
        int pos = atomicAdd(&p.cursor[d_], 1);
        p.csr_src[p.row_start[d_] + pos] = p.src[e];
    }
}

__device__ __forceinline__ void phase_agg(const Params& p, const unsigned short* hin,
                                          int bx, int gs) {
    int tid = threadIdx.x;
    int q = tid & 15;
    int ng = tid >> 4;
    for (int g = bx; g < NGROUPS; g += gs) {
        int node = g * 16 + ng;
        int d = p.deg[node];
        int pd = (d + 3) & ~3;
        int beg = p.row_start[node];
        float a[8] = {0.f, 0.f, 0.f, 0.f, 0.f, 0.f, 0.f, 0.f};
        float b[8] = {0.f, 0.f, 0.f, 0.f, 0.f, 0.f, 0.f, 0.f};
        for (int e = beg; e < beg + pd; e += 16) {
            int cnt = min(beg + pd - e, 16);
            int idx = p.csr_src[e + min(q, cnt - 1)];
            for (int j = 0; j < cnt; j += 4) {
                int s0 = __shfl(idx, j + 0, 16);
                int s1 = __shfl(idx, j + 1, 16);
                int s2 = __shfl(idx, j + 2, 16);
                int s3 = __shfl(idx, j + 3, 16);
                uint4 v0 = *((const uint4*)(hin + (size_t)s0 * D + q * 8));
                uint4 v1 = *((const uint4*)(hin + (size_t)s1 * D + q * 8));
                uint4 v2 = *((const uint4*)(hin + (size_t)s2 * D + q * 8));
                uint4 v3 = *((const uint4*)(hin + (size_t)s3 * D + q * 8));
                a[0] += bf_lo(v0.x); a[1] += bf_hi(v0.x);
                a[2] += bf_lo(v0.y); a[3] += bf_hi(v0.y);
                a[4] += bf_lo(v0.z); a[5] += bf_hi(v0.z);
                a[6] += bf_lo(v0.w); a[7] += bf_hi(v0.w);
                b[0] += bf_lo(v1.x); b[1] += bf_hi(v1.x);
                b[2] += bf_lo(v1.y); b[3] += bf_hi(v1.y);
                b[4] += bf_lo(v1.z); b[5] += bf_hi(v1.z);
                b[6] += bf_lo(v1.w); b[7] += bf_hi(v1.w);
                a[0] += bf_lo(v2.x); a[1] += bf_hi(v2.x);
                a[2] += bf_lo(v2.y); a[3] += bf_hi(v2.y);
                a[4] += bf_lo(v2.z); a[5] += bf_hi(v2.z);
                a[6] += bf_lo(v2.w); a[7] += bf_hi(v2.w);
                b[0] += bf_lo(v3.x); b[1] += bf_hi(v3.x);
                b[2] += bf_lo(v3.y); b[3] += bf_hi(v3.y);
                b[4] += bf_lo(v3.z); b[5] += bf_hi(v3.z);
                b[6] += bf_lo(v3.w); b[7] += bf_hi(v3.w);
            }
        }
        float w = p.inv_deg[node];
        uint4 o;
        o.x = (unsigned)f2bf((a[0] + b[0]) * w) | ((unsigned)f2bf((a[1] + b[1]) * w) << 16);
        o.y = (unsigned)f2bf((a[2] + b[2]) * w) | ((unsigned)f2bf((a[3] + b[3]) * w) << 16);
        o.z = (unsigned)f2bf((a[4] + b[4]) * w) | ((unsigned)f2bf((a[5] + b[5]) * w) << 16);
        o.w = (unsigned)f2bf((a[6] + b[6]) * w) | ((unsigned)f2bf((a[7] + b[7]) * w) << 16);
        *((uint4*)(p.aggb + (size_t)node * D + q * 8)) = o;
    }
}

__device__ __forceinline__ void phase_gemm(const Params& p, const unsigned short* hin,
                                           int l, int bx, int gs,
                                           unsigned short (*c_s)[32][CPITCH]) {
    const unsigned short* WtFl = p.WtF + (size_t)l * D * 256;
    const float* bl = p.bl + l * D;
    const short8* Bf = (const short8*)WtFl;
    int tid = threadIdx.x;
    int wave = tid >> 6;
    int lane = tid & 63;
    int half = lane & 15;
    int quad = lane >> 4;
    int kq = quad * 8;
    int last = (l == NLAYERS - 1);

    for (int t = bx * 4 + wave; t < NTILES; t += gs * 4) {
        int m0 = t * 32;
        floatx4 acc[2][8];
        #pragma unroll
        for (int mt = 0; mt < 2; mt++)
            #pragma unroll
            for (int j = 0; j < 8; j++)
                acc[mt][j] = (floatx4){0.f, 0.f, 0.f, 0.f};

        int r0 = min(m0 + half, N_NODES - 1);
        int r1 = min(m0 + 16 + half, N_NODES - 1);

        #pragma unroll
        for (int kt = 0; kt < 8; kt++) {
            const unsigned short* abase = (kt < 4) ? p.aggb : hin;
            int ka = (kt & 3) * 32 + kq;
            short8 a0 = *((const short8*)(abase + (size_t)r0 * D + ka));
            short8 a1 = *((const short8*)(abase + (size_t)r1 * D + ka));
            #pragma unroll
            for (int j = 0; j < 8; j++) {
                short8 b = Bf[(j * 8 + kt) * 64 + lane];
                acc[0][j] = __builtin_amdgcn_mfma_f32_16x16x32_bf16(a0, b, acc[0][j], 0, 0, 0);
                acc[1][j] = __builtin_amdgcn_mfma_f32_16x16x32_bf16(a1, b, acc[1][j], 0, 0, 0);
            }
        }

        if (!last) {
            // epilogue: bias+relu -> wave-private LDS slab -> coalesced global stores.
            // LDS ops from one wave execute in order; slab is wave-private -> no barrier.
            #pragma unroll
            for (int j = 0; j < 8; j++) {
                int col = j * 16 + half;
                float bv = bl[col];
                #pragma unroll
                for (int mt = 0; mt < 2; mt++)
                    #pragma unroll
                    for (int r = 0; r < 4; r++)
                        c_s[wave][mt * 16 + quad * 4 + r][col] =
                            f2bf(fmaxf(acc[mt][j][r] + bv, 0.f));
            }
            #pragma unroll
            for (int tt = 0; tt < 8; tt++) {
                int flat = tt * 64 + lane;
                int rl = flat >> 4;
                int c = flat & 15;
                int row = m0 + rl;
                if (row < N_NODES)
                    *((uint4*)(p.hb + (size_t)row * D + c * 8)) =
                        *((const uint4*)&c_s[wave][rl][c * 8]);
            }
        } else {
            float vout[2][4] = {{0.f, 0.f, 0.f, 0.f}, {0.f, 0.f, 0.f, 0.f}};
            #pragma unroll
            for (int j = 0; j < 8; j++) {
                int col = j * 16 + half;
                float bv = bl[col];
                float wv = p.Wout[col];
                #pragma unroll
                for (int mt = 0; mt < 2; mt++)
                    #pragma unroll
                    for (int r = 0; r < 4; r++)
                        vout[mt][r] += fmaxf(acc[mt][j][r] + bv, 0.f) * wv;
            }
            #pragma unroll
            for (int off = 1; off < 16; off <<= 1) {
                #pragma unroll
                for (int mt = 0; mt < 2; mt++)
                    #pragma unroll
                    for (int r = 0; r < 4; r++)
                        vout[mt][r] += __shfl_xor(vout[mt][r], off, 64);
            }
            if (half == 0) {
                float bo = p.bout[0];
                #pragma unroll
                for (int mt = 0; mt < 2; mt++) {
                    #pragma unroll
                    for (int r = 0; r < 4; r++) {
                        int row = m0 + mt * 16 + quad * 4 + r;
                        if (row < N_NODES) p.out[row] = vout[mt][r] + bo;
                    }
                }
            }
        }
    }
}

// ---------------- cooperative mega-kernel ----------------
// __launch_bounds__(256, 2): 2 blocks/CU guaranteed schedulable (<=256 VGPR,
// 2x34.8 KB LDS < 160 KB) so a 512-block cooperative launch must be accepted.

__global__ __launch_bounds__(256, 2) void mega_kernel(Params p) {
    cg::grid_group grid = cg::this_grid();
    __shared__ unsigned short c_s[4][32][CPITCH];
    const int bx = blockIdx.x;
    const int gs = gridDim.x;

    phase_cvt(p, bx, gs);
    grid.sync();
    phase_hist(p, bx, gs);
    grid.sync();
    phase_alloc(p, bx, gs);
    grid.sync();
    phase_fill(p, bx, gs);
    grid.sync();

    for (int l = 0; l < NLAYERS; l++) {
        const unsigned short* hin = (l == 0) ? p.xb : p.hb;
        phase_agg(p, hin, bx, gs);
        grid.sync();
        phase_gemm(p, hin, l, bx, gs, c_s);
        if (l < NLAYERS - 1) grid.sync();
    }
}

// ---------------- non-cooperative fallback kernels (identical math) ----------------

__global__ __launch_bounds__(256) void k_cvt(Params p)  { phase_cvt(p, blockIdx.x, gridDim.x); }
__global__ __launch_bounds__(256) void k_hist(Params p) { phase_hist(p, blockIdx.x, gridDim.x); }
__global__ __launch_bounds__(256) void k_alloc(Params p){ phase_alloc(p, blockIdx.x, gridDim.x); }
__global__ __launch_bounds__(256) void k_fill(Params p) { phase_fill(p, blockIdx.x, gridDim.x); }
__global__ __launch_bounds__(256) void k_agg(Params p, int l) {
    const unsigned short* hin = (l == 0) ? p.xb : p.hb;
    phase_agg(p, hin, blockIdx.x, gridDim.x);
}
__global__ __launch_bounds__(256, 2) void k_gemm(Params p, int l) {
    __shared__ unsigned short c_s[4][32][CPITCH];
    const unsigned short* hin = (l == 0) ? p.xb : p.hb;
    phase_gemm(p, hin, l, blockIdx.x, gridDim.x, c_s);
}

// ---------------- launch ----------------

extern "C" void kernel_launch(void* const* d_in, const int* in_sizes, int n_in,
                              void* d_out, int out_size, void* d_ws, size_t ws_size,
                              hipStream_t stream) {
    char* ws = (char*)d_ws;
    size_t off = 0;
    auto alloc = [&](size_t bytes) -> void* {
        void* p = ws + off;
        off += (bytes + 255) & ~(size_t)255;
        return p;
    };

    Params p;
    p.x    = (const float*)d_in[0];
    const int* edge = (const int*)d_in[1];
    p.src  = edge;
    p.dst  = edge + N_EDGES;
    p.Wl   = (const float*)d_in[2];
    p.bl   = (const float*)d_in[3];
    p.Wr   = (const float*)d_in[4];
    p.Wout = (const float*)d_in[5];
    p.bout = (const float*)d_in[6];
    p.out  = (float*)d_out;

    p.xb        = (unsigned short*)alloc((size_t)(N_NODES + 1) * D * 2);
    p.hb        = (unsigned short*)alloc((size_t)(N_NODES + 1) * D * 2);
    p.aggb      = (unsigned short*)alloc((size_t)N_NODES * D * 2);
    p.WtF       = (unsigned short*)alloc((size_t)NLAYERS * D * 256 * 2);
    p.deg       = (int*)alloc((size_t)N_NODES * sizeof(int));
    p.row_start = (int*)alloc((size_t)N_NODES * sizeof(int));
    p.cursor    = (int*)alloc((size_t)N_NODES * sizeof(int));
    p.inv_deg   = (float*)alloc((size_t)N_NODES * sizeof(float));
    p.csr_src   = (int*)alloc((size_t)CSR_CAP * sizeof(int));
    p.counter   = (int*)alloc(256);

    void* args[] = { &p };
    hipError_t err = hipLaunchCooperativeKernel(
        reinterpret_cast<void*>(mega_kernel), dim3(512), dim3(256), args, 0, stream);

    if (err != hipSuccess) {
        (void)hipGetLastError();   // clear sticky error, run equivalent fallback
        k_cvt<<<(CVT_TOTAL + 255) / 256, 256, 0, stream>>>(p);
        k_hist<<<(N_EDGES + 255) / 256, 256, 0, stream>>>(p);
        k_alloc<<<196, 256, 0, stream>>>(p);
        k_fill<<<(N_EDGES + 255) / 256, 256, 0, stream>>>(p);
        for (int l = 0; l < NLAYERS; l++) {
            k_agg<<<NGROUPS, 256, 0, stream>>>(p, l);
            k_gemm<<<(NTILES + 3) / 4, 256, 0, stream>>>(p, l);
        }
    }
}

// Round 11
// 286.591 us; speedup vs baseline: 3.0382x; 3.0382x over previous
//
#include <hip/hip_runtime.h>

#define N_NODES 50000
#define N_EDGES 600000
#define D 128
#define NLAYERS 3
#define CSR_CAP (N_EDGES + 3 * N_NODES)   // padded CSR worst case

typedef __attribute__((ext_vector_type(8))) short short8;
typedef __attribute__((ext_vector_type(4))) float floatx4;

__device__ __forceinline__ float bf_lo(unsigned u) { return __uint_as_float(u << 16); }
__device__ __forceinline__ float bf_hi(unsigned u) { return __uint_as_float(u & 0xffff0000u); }
__device__ __forceinline__ unsigned short f2bf(float f) {
    unsigned u = __float_as_uint(f);
    return (unsigned short)((u + 0x7fffu + ((u >> 16) & 1u)) >> 16);
}

// ---------------- merged: x->bf16, WtF build, zero-init (incl. sentinel rows) --------
// section A: [0, CVT_A)           one float4 of x -> ushort4 of xb
// section B: [CVT_A, +CVT_B)      one bf16 element of WtF (MFMA B-fragment order)
// section C: [+CVT_B, +N_NODES)   zero deg/cursor; j==0 zeroes counter; j<D zeroes pad rows

#define CVT_A (N_NODES * D / 4)              // 1,600,000
#define CVT_B (NLAYERS * D * 256)            // 98,304
#define CVT_TOTAL (CVT_A + CVT_B + N_NODES)

__global__ void cvt_init_kernel(const float* __restrict__ x, const float* __restrict__ Wl,
                                const float* __restrict__ Wr,
                                unsigned short* __restrict__ xb, unsigned short* __restrict__ hb,
                                unsigned short* __restrict__ WtF,
                                int* __restrict__ deg, int* __restrict__ cursor,
                                int* __restrict__ counter) {
    int i = blockIdx.x * blockDim.x + threadIdx.x;
    if (i < CVT_A) {
        float4 v = ((const float4*)x)[i];
        ushort4 o;
        o.x = f2bf(v.x); o.y = f2bf(v.y); o.z = f2bf(v.z); o.w = f2bf(v.w);
        ((ushort4*)xb)[i] = o;
    } else if (i < CVT_A + CVT_B) {
        int t = i - CVT_A;
        int l = t >> 15;
        int r = t & 32767;
        int f = r >> 3;
        int ii = r & 7;
        int jkt = f >> 6;
        int lane = f & 63;
        int j = jkt >> 3;
        int kt = jkt & 7;
        int half = lane & 15;
        int quad = lane >> 4;
        int n = j * 16 + half;
        int k = kt * 32 + quad * 8 + ii;
        float v = (k < D) ? Wl[(size_t)l * D * D + (size_t)k * D + n]
                          : Wr[(size_t)l * D * D + (size_t)(k - D) * D + n];
        WtF[t] = f2bf(v);
    } else if (i < CVT_TOTAL) {
        int j = i - (CVT_A + CVT_B);
        deg[j] = 0;
        cursor[j] = 0;
        if (j == 0) counter[0] = 0;
        if (j < D) {                         // zero the sentinel row N_NODES
            xb[(size_t)N_NODES * D + j] = 0;
            hb[(size_t)N_NODES * D + j] = 0;
        }
    }
}

// ---------------- CSR build ----------------

__global__ void hist_kernel(const int* __restrict__ dst, int* __restrict__ deg) {
    int e = blockIdx.x * blockDim.x + threadIdx.x;
    if (e < N_EDGES) atomicAdd(&deg[dst[e]], 1);
}

// row_start via per-wave scan of PADDED sizes + one atomicAdd per wave; writes sentinel pads
__global__ void alloc_kernel(const int* __restrict__ deg, int* __restrict__ counter,
                             int* __restrict__ row_start, float* __restrict__ inv_deg,
                             int* __restrict__ csr_src) {
    int i = blockIdx.x * blockDim.x + threadIdx.x;
    int lane = threadIdx.x & 63;
    int d = (i < N_NODES) ? deg[i] : 0;
    int pd = (d + 3) & ~3;
    int v = pd;
    #pragma unroll
    for (int off = 1; off < 64; off <<= 1) {
        int t = __shfl_up(v, off, 64);
        if (lane >= off) v += t;
    }
    int total = __shfl(v, 63, 64);
    int base = 0;
    if (lane == 63) base = atomicAdd(counter, total);
    base = __shfl(base, 63, 64);
    if (i < N_NODES) {
        int rs = base + v - pd;
        row_start[i] = rs;
        inv_deg[i] = 1.0f / fmaxf((float)d, 1.0f);
        for (int k = d; k < pd; k++) csr_src[rs + k] = N_NODES;   // sentinel pads
    }
}

__global__ void fill_kernel(const int* __restrict__ src, const int* __restrict__ dst,
                            const int* __restrict__ row_start, int* __restrict__ cursor,
                            int* __restrict__ csr_src) {
    int e = blockIdx.x * blockDim.x + threadIdx.x;
    if (e < N_EDGES) {
        int d_ = dst[e];
        int pos = atomicAdd(&cursor[d_], 1);
        csr_src[row_start[d_] + pos] = src[e];
    }
}

// ---------------- mean aggregation: lane-preloaded indices + 4 loads in flight ----------
// 16 nodes per 256-thread block; 16 lanes per node, 16B per lane.
// Rows padded to multiple of 4 with sentinel (zero) rows -> exact unroll-4.

__global__ void agg_kernel(const unsigned short* __restrict__ h, const int* __restrict__ row_start,
                           const int* __restrict__ deg, const int* __restrict__ csr_src,
                           const float* __restrict__ inv_deg, unsigned short* __restrict__ agg) {
    int node = blockIdx.x * 16 + (threadIdx.x >> 4);
    int q = threadIdx.x & 15;
    if (node >= N_NODES) return;
    int d = deg[node];
    int pd = (d + 3) & ~3;
    int beg = row_start[node];
    float a[8] = {0.f, 0.f, 0.f, 0.f, 0.f, 0.f, 0.f, 0.f};
    float b[8] = {0.f, 0.f, 0.f, 0.f, 0.f, 0.f, 0.f, 0.f};
    for (int e = beg; e < beg + pd; e += 16) {
        int cnt = min(beg + pd - e, 16);                 // multiple of 4
        int idx = csr_src[e + min(q, cnt - 1)];          // coalesced preload of 16 indices
        for (int j = 0; j < cnt; j += 4) {
            int s0 = __shfl(idx, j + 0, 16);
            int s1 = __shfl(idx, j + 1, 16);
            int s2 = __shfl(idx, j + 2, 16);
            int s3 = __shfl(idx, j + 3, 16);
            uint4 v0 = *((const uint4*)(h + (size_t)s0 * D + q * 8));
            uint4 v1 = *((const uint4*)(h + (size_t)s1 * D + q * 8));
            uint4 v2 = *((const uint4*)(h + (size_t)s2 * D + q * 8));
            uint4 v3 = *((const uint4*)(h + (size_t)s3 * D + q * 8));
            a[0] += bf_lo(v0.x); a[1] += bf_hi(v0.x);
            a[2] += bf_lo(v0.y); a[3] += bf_hi(v0.y);
            a[4] += bf_lo(v0.z); a[5] += bf_hi(v0.z);
            a[6] += bf_lo(v0.w); a[7] += bf_hi(v0.w);
            b[0] += bf_lo(v1.x); b[1] += bf_hi(v1.x);
            b[2] += bf_lo(v1.y); b[3] += bf_hi(v1.y);
            b[4] += bf_lo(v1.z); b[5] += bf_hi(v1.z);
            b[6] += bf_lo(v1.w); b[7] += bf_hi(v1.w);
            a[0] += bf_lo(v2.x); a[1] += bf_hi(v2.x);
            a[2] += bf_lo(v2.y); a[3] += bf_hi(v2.y);
            a[4] += bf_lo(v2.z); a[5] += bf_hi(v2.z);
            a[6] += bf_lo(v2.w); a[7] += bf_hi(v2.w);
            b[0] += bf_lo(v3.x); b[1] += bf_hi(v3.x);
            b[2] += bf_lo(v3.y); b[3] += bf_hi(v3.y);
            b[4] += bf_lo(v3.z); b[5] += bf_hi(v3.z);
            b[6] += bf_lo(v3.w); b[7] += bf_hi(v3.w);
        }
    }
    float w = inv_deg[node];
    uint4 o;
    o.x = (unsigned)f2bf((a[0] + b[0]) * w) | ((unsigned)f2bf((a[1] + b[1]) * w) << 16);
    o.y = (unsigned)f2bf((a[2] + b[2]) * w) | ((unsigned)f2bf((a[3] + b[3]) * w) << 16);
    o.z = (unsigned)f2bf((a[4] + b[4]) * w) | ((unsigned)f2bf((a[5] + b[5]) * w) << 16);
    o.w = (unsigned)f2bf((a[6] + b[6]) * w) | ((unsigned)f2bf((a[7] + b[7]) * w) << 16);
    *((uint4*)(agg + (size_t)node * D + q * 8)) = o;
}

// ---------------- MFMA GEMM: hout = relu([agg|hin](bf16) @ W^T + bias) ----------------
// One wave per block, 32 rows x 128 cols, K=256. B from fragment-layout WtF (coalesced).

#define CPITCH 136

__global__ __launch_bounds__(64) void gemm_mfma_kernel(
    const unsigned short* __restrict__ aggb, const unsigned short* __restrict__ hinb,
    const unsigned short* __restrict__ WtF, const float* __restrict__ bias,
    unsigned short* __restrict__ hout) {
    __shared__ unsigned short c_s[32][CPITCH];

    int m0 = blockIdx.x * 32;
    int lane = threadIdx.x;
    int half = lane & 15;
    int quad = lane >> 4;
    int kq = quad * 8;

    floatx4 acc[2][8];
    #pragma unroll
    for (int mt = 0; mt < 2; mt++)
        #pragma unroll
        for (int j = 0; j < 8; j++)
            acc[mt][j] = (floatx4){0.f, 0.f, 0.f, 0.f};

    int r0 = min(m0 + half, N_NODES - 1);
    int r1 = min(m0 + 16 + half, N_NODES - 1);

    const short8* Bf = (const short8*)WtF;
    #pragma unroll
    for (int kt = 0; kt < 8; kt++) {
        const unsigned short* abase = (kt < 4) ? aggb : hinb;
        int ka = (kt & 3) * 32 + kq;
        short8 a0 = *((const short8*)(abase + (size_t)r0 * D + ka));
        short8 a1 = *((const short8*)(abase + (size_t)r1 * D + ka));
        #pragma unroll
        for (int j = 0; j < 8; j++) {
            short8 b = Bf[(j * 8 + kt) * 64 + lane];
            acc[0][j] = __builtin_amdgcn_mfma_f32_16x16x32_bf16(a0, b, acc[0][j], 0, 0, 0);
            acc[1][j] = __builtin_amdgcn_mfma_f32_16x16x32_bf16(a1, b, acc[1][j], 0, 0, 0);
        }
    }

    #pragma unroll
    for (int j = 0; j < 8; j++) {
        int col = j * 16 + half;
        float bv = bias[col];
        #pragma unroll
        for (int mt = 0; mt < 2; mt++)
            #pragma unroll
            for (int r = 0; r < 4; r++)
                c_s[mt * 16 + quad * 4 + r][col] = f2bf(fmaxf(acc[mt][j][r] + bv, 0.f));
    }
    __syncthreads();
    #pragma unroll
    for (int t = 0; t < 8; t++) {
        int flat = t * 64 + lane;
        int rl = flat >> 4;
        int c = flat & 15;
        int row = m0 + rl;
        if (row < N_NODES)
            *((uint4*)(hout + (size_t)row * D + c * 8)) = *((const uint4*)&c_s[rl][c * 8]);
    }
}

// ---------------- last layer: GEMM + fused readout ----------------

__global__ __launch_bounds__(64) void gemm_mfma_out_kernel(
    const unsigned short* __restrict__ aggb, const unsigned short* __restrict__ hinb,
    const unsigned short* __restrict__ WtF, const float* __restrict__ bias,
    const float* __restrict__ Wout, const float* __restrict__ bout,
    float* __restrict__ out) {
    int m0 = blockIdx.x * 32;
    int lane = threadIdx.x;
    int half = lane & 15;
    int quad = lane >> 4;
    int kq = quad * 8;

    floatx4 acc[2][8];
    #pragma unroll
    for (int mt = 0; mt < 2; mt++)
        #pragma unroll
        for (int j = 0; j < 8; j++)
            acc[mt][j] = (floatx4){0.f, 0.f, 0.f, 0.f};

    int r0 = min(m0 + half, N_NODES - 1);
    int r1 = min(m0 + 16 + half, N_NODES - 1);

    const short8* Bf = (const short8*)WtF;
    #pragma unroll
    for (int kt = 0; kt < 8; kt++) {
        const unsigned short* abase = (kt < 4) ? aggb : hinb;
        int ka = (kt & 3) * 32 + kq;
        short8 a0 = *((const short8*)(abase + (size_t)r0 * D + ka));
        short8 a1 = *((const short8*)(abase + (size_t)r1 * D + ka));
        #pragma unroll
        for (int j = 0; j < 8; j++) {
            short8 b = Bf[(j * 8 + kt) * 64 + lane];
            acc[0][j] = __builtin_amdgcn_mfma_f32_16x16x32_bf16(a0, b, acc[0][j], 0, 0, 0);
            acc[1][j] = __builtin_amdgcn_mfma_f32_16x16x32_bf16(a1, b, acc[1][j], 0, 0, 0);
        }
    }

    float vout[2][4] = {{0.f, 0.f, 0.f, 0.f}, {0.f, 0.f, 0.f, 0.f}};
    #pragma unroll
    for (int j = 0; j < 8; j++) {
        int col = j * 16 + half;
        float bv = bias[col];
        float wv = Wout[col];
        #pragma unroll
        for (int mt = 0; mt < 2; mt++)
            #pragma unroll
            for (int r = 0; r < 4; r++)
                vout[mt][r] += fmaxf(acc[mt][j][r] + bv, 0.f) * wv;
    }
    #pragma unroll
    for (int off = 1; off < 16; off <<= 1) {
        #pragma unroll
        for (int mt = 0; mt < 2; mt++)
            #pragma unroll
            for (int r = 0; r < 4; r++)
                vout[mt][r] += __shfl_xor(vout[mt][r], off, 64);
    }
    if (half == 0) {
        float bo = bout[0];
        #pragma unroll
        for (int mt = 0; mt < 2; mt++) {
            #pragma unroll
            for (int r = 0; r < 4; r++) {
                int row = m0 + mt * 16 + quad * 4 + r;
                if (row < N_NODES) out[row] = vout[mt][r] + bo;
            }
        }
    }
}

// ---------------- launch ----------------

extern "C" void kernel_launch(void* const* d_in, const int* in_sizes, int n_in,
                              void* d_out, int out_size, void* d_ws, size_t ws_size,
                              hipStream_t stream) {
    const float* x     = (const float*)d_in[0];
    const int*   edge  = (const int*)d_in[1];   // [2, E]: src then dst
    const float* W_l   = (const float*)d_in[2];
    const float* b_l   = (const float*)d_in[3];
    const float* W_r   = (const float*)d_in[4];
    const float* W_out = (const float*)d_in[5];
    const float* b_out = (const float*)d_in[6];
    float* out = (float*)d_out;

    char* ws = (char*)d_ws;
    size_t off = 0;
    auto alloc = [&](size_t bytes) -> void* {
        void* p = ws + off;
        off += (bytes + 255) & ~(size_t)255;
        return p;
    };
    unsigned short* xb   = (unsigned short*)alloc((size_t)(N_NODES + 1) * D * 2);
    unsigned short* hb   = (unsigned short*)alloc((size_t)(N_NODES + 1) * D * 2);
    unsigned short* aggb = (unsigned short*)alloc((size_t)N_NODES * D * 2);
    unsigned short* WtF  = (unsigned short*)alloc((size_t)NLAYERS * D * 256 * 2);
    int*   deg       = (int*)alloc((size_t)N_NODES * sizeof(int));
    int*   row_start = (int*)alloc((size_t)N_NODES * sizeof(int));
    int*   cursor    = (int*)alloc((size_t)N_NODES * sizeof(int));
    float* inv_deg   = (float*)alloc((size_t)N_NODES * sizeof(float));
    int*   csr_src   = (int*)alloc((size_t)CSR_CAP * sizeof(int));
    int*   counter   = (int*)alloc(256);

    const int* src = edge;
    const int* dst = edge + N_EDGES;

    cvt_init_kernel<<<(CVT_TOTAL + 255) / 256, 256, 0, stream>>>(
        x, W_l, W_r, xb, hb, WtF, deg, cursor, counter);
    hist_kernel<<<(N_EDGES + 255) / 256, 256, 0, stream>>>(dst, deg);
    alloc_kernel<<<(N_NODES + 255) / 256, 256, 0, stream>>>(deg, counter, row_start, inv_deg, csr_src);
    fill_kernel<<<(N_EDGES + 255) / 256, 256, 0, stream>>>(src, dst, row_start, cursor, csr_src);

    const int agg_grid  = (N_NODES + 15) / 16;
    const int gemm_grid = (N_NODES + 31) / 32;

    // layer 0: xb -> hb
    agg_kernel<<<agg_grid, 256, 0, stream>>>(xb, row_start, deg, csr_src, inv_deg, aggb);
    gemm_mfma_kernel<<<gemm_grid, 64, 0, stream>>>(aggb, xb, WtF, b_l, hb);
    // layer 1: hb -> hb (row-exclusive, safe in-place; sentinel row untouched/zero)
    agg_kernel<<<agg_grid, 256, 0, stream>>>(hb, row_start, deg, csr_src, inv_deg, aggb);
    gemm_mfma_kernel<<<gemm_grid, 64, 0, stream>>>(aggb, hb,
        WtF + (size_t)1 * D * 256, b_l + 1 * D, hb);
    // layer 2: hb -> out (fused readout)
    agg_kernel<<<agg_grid, 256, 0, stream>>>(hb, row_start, deg, csr_src, inv_deg, aggb);
    gemm_mfma_out_kernel<<<gemm_grid, 64, 0, stream>>>(aggb, hb,
        WtF + (size_t)2 * D * 256, b_l + 2 * D, W_out, b_out, out);
}